// Round 15
// baseline (68.868 us; speedup 1.0000x reference)
//
#include <hip/hip_runtime.h>
#include <hip/hip_bf16.h>

#define I_DIM 4096
#define J_DIM 4096
#define NPERM0 10
#define NPERM1 10
#define RROWS 4            // rows per K1 block
#define CHUNKS 8           // column chunks == XCD count
#define CCOLS (J_DIM / CHUNKS)   // 512 cols per chunk (4 MiB bf16 slice)
#define K2_ROWS 16         // out rows per K2 block (4 waves x 4 rows)

typedef float          f32x4 __attribute__((ext_vector_type(4)));
typedef int            i32x4 __attribute__((ext_vector_type(4)));
typedef unsigned short u16x4 __attribute__((ext_vector_type(4)));
typedef unsigned short u16x8 __attribute__((ext_vector_type(8)));

// XOR-swizzle for 8-byte LDS slots: physical = s ^ ((s>>4)&7). Bijective.
// Transpose writes (s = 8*c8+k, fixed k): 16 consecutive lanes hit 16
// distinct low-4 slots -> all 32 banks exactly 4x per wave (b64 optimum).
__device__ __forceinline__ int swzB(int s) { return s ^ ((s >> 4) & 7); }

__device__ __forceinline__ float bf2f(unsigned short u) {
    return __uint_as_float((unsigned)u << 16);
}
__device__ __forceinline__ unsigned short f2bf(float f) {
    unsigned u = __float_as_uint(f);
    u += 0x7FFFu + ((u >> 16) & 1u);
    return (unsigned short)(u >> 16);
}

// soft mask: clip((xi-gamma)*sigmoid(x)+gamma, 0, 1), xi=1.1, gamma=-0.1
__device__ __forceinline__ float soft_mask(float x) {
    float s = 1.0f / (1.0f + __expf(-x));
    return fminf(fmaxf(1.2f * s - 0.1f, 0.0f), 1.0f);
}

// K1: fused soft-mask + column-mix (round-11/14 proven body, VGPR 40):
//   u[i,c] = sum_q ps1[q,c] * sw[i, perm1[q,c]],  sw[i,j] = w[i,j]*mask(m[i,j])
// w/m loads CACHED (round 14: +10 us vs NT — L3 retains them across replays).
// launch_bounds(512,6): cap 85 VGPR, comfortably above the 40 this body
// uses -> 3 blocks/CU (24 waves, was 2 blocks/16 waves at (512,4)). A third
// resident block overlaps its stream phase with others' gather phase.
// SPILL RULE (rounds 7/12/13): caps at or below ~64 on these bodies squeeze
// VGPR to 32 and spill (WRITE_SIZE balloons). Cap 85 >> 40 is benign.
__global__ __launch_bounds__(512, 6) void maskcolmix_kernel(
    const float* __restrict__ w,              // (I, J) f32
    const float* __restrict__ m,              // (I, J) f32
    const float* __restrict__ ps1,            // (NPERM1, J)
    const int*   __restrict__ perm1,          // (NPERM1, J)
    unsigned short* __restrict__ ub) {        // (I, J) bf16 out
    __shared__ u16x4 vlds[J_DIM];             // 32 KiB

    const int i0 = blockIdx.x * RROWS;
    const int c8 = threadIdx.x;               // column octet, 0..511

    // Load w,m (8 cols x 4 rows, cached), compute sw bf16 in-register.
    u16x8 rowv[RROWS];
#pragma unroll
    for (int r = 0; r < RROWS; ++r) {
        const f32x4* w4 = reinterpret_cast<const f32x4*>(
                              w + (size_t)(i0 + r) * J_DIM) + 2 * c8;
        const f32x4* m4 = reinterpret_cast<const f32x4*>(
                              m + (size_t)(i0 + r) * J_DIM) + 2 * c8;
        f32x4 w0 = w4[0];
        f32x4 w1 = w4[1];
        f32x4 m0 = m4[0];
        f32x4 m1 = m4[1];
        u16x8 o;
#pragma unroll
        for (int k = 0; k < 4; ++k) {
            o[k]     = f2bf(w0[k] * soft_mask(m0[k]));
            o[k + 4] = f2bf(w1[k] * soft_mask(m1[k]));
        }
        rowv[r] = o;
    }
    // Transpose into LDS (swizzled, conflict-free b64).
#pragma unroll
    for (int k = 0; k < 8; ++k) {
        u16x4 t;
#pragma unroll
        for (int r = 0; r < RROWS; ++r) t[r] = rowv[r][k];
        vlds[swzB(8 * c8 + k)] = t;
    }
    __syncthreads();

    // Column gather + combine.
    float o[RROWS][8];
#pragma unroll
    for (int r = 0; r < RROWS; ++r)
#pragma unroll
        for (int k = 0; k < 8; ++k) o[r][k] = 0.f;

#pragma unroll 2
    for (int q = 0; q < NPERM1; ++q) {
        const i32x4* pq = reinterpret_cast<const i32x4*>(perm1 + (size_t)q * J_DIM);
        const f32x4* sq = reinterpret_cast<const f32x4*>(ps1  + (size_t)q * J_DIM);
        i32x4 pc0 = pq[2 * c8];
        i32x4 pc1 = pq[2 * c8 + 1];
        f32x4 s0  = sq[2 * c8];
        f32x4 s1  = sq[2 * c8 + 1];
        u16x4 g[8];
#pragma unroll
        for (int k = 0; k < 4; ++k) {
            g[k]     = vlds[swzB(pc0[k])];
            g[k + 4] = vlds[swzB(pc1[k])];
        }
#pragma unroll
        for (int k = 0; k < 4; ++k) {
#pragma unroll
            for (int r = 0; r < RROWS; ++r) {
                o[r][k]     += s0[k] * bf2f(g[k][r]);
                o[r][k + 4] += s1[k] * bf2f(g[k + 4][r]);
            }
        }
    }
    // Emit u as bf16 (cached: read by K2 soon, let it live in L2/L3).
#pragma unroll
    for (int r = 0; r < RROWS; ++r) {
        u16x8 ob;
#pragma unroll
        for (int k = 0; k < 8; ++k) ob[k] = f2bf(o[r][k]);
        *reinterpret_cast<u16x8*>(ub + (size_t)(i0 + r) * J_DIM + (size_t)c8 * 8) = ob;
    }
}

// K2: row-mix on u -> final out (f32):
//   out[i,c] = sum_p ps0[p,i] * u[perm0[p,i], c]
// Column-chunked (chunk = bid % 8 -> XCD): each XCD gathers from a 4 MiB
// u slice resident in its L2. NT out stores keep that slice unevicted.
// launch_bounds(256,6): cap 85 >= the 64 this body uses -> 6 blocks/CU
// (24 waves, was 4 blocks/16 waves) for more outstanding L2 gathers.
__global__ __launch_bounds__(256, 6) void rowmix_out_kernel(
    const unsigned short* __restrict__ ub,    // (I, J) bf16
    const float* __restrict__ ps0,            // (NPERM0, I)
    const int*   __restrict__ perm0,          // (NPERM0, I)
    float* __restrict__ out) {                // (I, J) f32
    const int chunk = blockIdx.x & (CHUNKS - 1);
    const int rg    = blockIdx.x / CHUNKS;
    const int wave  = threadIdx.x >> 6;
    const int lane  = threadIdx.x & 63;
    const int i0    = rg * K2_ROWS + wave * 4;           // 4 rows per wave
    const size_t colbase = (size_t)chunk * CCOLS + (size_t)lane * 8;

    float acc[4][8];
#pragma unroll
    for (int r = 0; r < 4; ++r)
#pragma unroll
        for (int k = 0; k < 8; ++k) acc[r][k] = 0.f;

#pragma unroll 2
    for (int p = 0; p < NPERM0; ++p) {
        u16x8 vv[4];
#pragma unroll
        for (int r = 0; r < 4; ++r) {
            int row = perm0[p * I_DIM + i0 + r];          // wave-uniform
            vv[r] = *reinterpret_cast<const u16x8*>(
                        ub + (size_t)row * J_DIM + colbase);
        }
#pragma unroll
        for (int r = 0; r < 4; ++r) {
            float s = ps0[p * I_DIM + i0 + r];            // wave-uniform
#pragma unroll
            for (int k = 0; k < 8; ++k) acc[r][k] += s * bf2f(vv[r][k]);
        }
    }
#pragma unroll
    for (int r = 0; r < 4; ++r) {
        f32x4 t0, t1;
#pragma unroll
        for (int k = 0; k < 4; ++k) { t0[k] = acc[r][k]; t1[k] = acc[r][k + 4]; }
        float* dst = out + (size_t)(i0 + r) * J_DIM + colbase;
        __builtin_nontemporal_store(t0, reinterpret_cast<f32x4*>(dst));
        __builtin_nontemporal_store(t1, reinterpret_cast<f32x4*>(dst) + 1);
    }
}

extern "C" void kernel_launch(void* const* d_in, const int* in_sizes, int n_in,
                              void* d_out, int out_size, void* d_ws, size_t ws_size,
                              hipStream_t stream) {
    const float* weight = (const float*)d_in[0];
    const float* smask  = (const float*)d_in[1];
    const float* ps0    = (const float*)d_in[2];
    const float* ps1    = (const float*)d_in[3];
    const int*   perm0  = (const int*)d_in[4];
    const int*   perm1  = (const int*)d_in[5];
    float* out = (float*)d_out;

    unsigned short* ub = (unsigned short*)d_ws;   // 32 MiB intermediate u

    maskcolmix_kernel<<<I_DIM / RROWS, 512, 0, stream>>>(
        weight, smask, ps1, perm1, ub);
    rowmix_out_kernel<<<CHUNKS * (I_DIM / K2_ROWS), 256, 0, stream>>>(
        ub, ps0, perm0, out);
}